// Round 14
// baseline (267.312 us; speedup 1.0000x reference)
//
#include <hip/hip_runtime.h>

// ARCQuantLayer: out = q(x)·q(W)^T + (x-q(x))[:,idx]·arc^T, q(v)=round(v*8)/8.
// r14 = r12 structure, but B is NOT LDS-staged: B fragments load straight from
// global (L1/L2-resident, 16KB/tile/block) into registers, 1 tile ahead.
// Rationale: r9/r11/r12/r13 all measured tile = MFMA(1306) + LDS(1152) summed;
// schedule variants can't overlap the pipes (1 block/CU lockstep), so cut the
// LDS term instead: -4 B ds_reads/wave and -16KB DMA writes per tile.
// INT8 main GEMM exact (|round(v*8)|<=~46, sums < 2^24, /64 pow2-exact).
// Comp (K=204->256) = 8 bf16 K-tiles after in-place i32->f32 convert.

#define M_DIM 8192
#define N_DIM 4096
#define K_DIM 4096
#define KO_PAD 256
#define K_PAD (K_DIM + KO_PAD)   // bf16 fallback layout
#define NT8 (K_DIM / 64)         // 64 i8 K-tiles (BK=64)
#define NTC (KO_PAD / 32)        // 8 comp bf16 K-tiles
#define GRP 544                  // prep groups/row: 512 i8 + 32 comp

typedef __bf16 bf16x8 __attribute__((ext_vector_type(8)));
typedef float f32x4 __attribute__((ext_vector_type(4)));
typedef int i32x4 __attribute__((ext_vector_type(4)));
typedef char c8 __attribute__((ext_vector_type(8)));

__device__ __forceinline__ void async16(const void* g, void* l) {
  __builtin_amdgcn_global_load_lds(
      (__attribute__((address_space(1))) void*)g,
      (__attribute__((address_space(3))) void*)l, 16, 0, 0);
}

__device__ __forceinline__ float qf(float f) { return rintf(f * 8.0f) * 0.125f; }
__device__ __forceinline__ __bf16 qbf(float f) { return (__bf16)qf(f); }

// ---- prep x -> A8 (int8, M x 4096) + Acomp (bf16, M x 256 residuals, pad 0)
__global__ __launch_bounds__(256) void prep_x8_kernel(const float* __restrict__ x,
                                                      const int* __restrict__ idx,
                                                      char* __restrict__ A8,
                                                      __bf16* __restrict__ Ac, int no) {
  int gid = blockIdx.x * 256 + threadIdx.x;
  int ml = gid / GRP;
  int g = gid - ml * GRP;
  const float* xr = x + (size_t)ml * K_DIM;
  if (g < 512) {
    int kk = g * 8;
    float4 v0 = *(const float4*)(xr + kk);
    float4 v1 = *(const float4*)(xr + kk + 4);
    c8 r;
    r[0] = (char)(int)rintf(v0.x * 8.0f); r[1] = (char)(int)rintf(v0.y * 8.0f);
    r[2] = (char)(int)rintf(v0.z * 8.0f); r[3] = (char)(int)rintf(v0.w * 8.0f);
    r[4] = (char)(int)rintf(v1.x * 8.0f); r[5] = (char)(int)rintf(v1.y * 8.0f);
    r[6] = (char)(int)rintf(v1.z * 8.0f); r[7] = (char)(int)rintf(v1.w * 8.0f);
    *(c8*)(A8 + (size_t)ml * K_DIM + kk) = r;
  } else {
    int j0 = (g - 512) * 8;
    bf16x8 r;
#pragma unroll
    for (int u = 0; u < 8; ++u) {
      float v = 0.f;
      int jj = j0 + u;
      if (jj < no) {
        float xv = xr[idx[jj]];
        v = xv - qf(xv);
      }
      r[u] = (__bf16)v;
    }
    *(bf16x8*)(Ac + (size_t)ml * KO_PAD + j0) = r;
  }
}

// ---- prep W -> B8 (int8, N x 4096) + Bcomp (bf16, N x 256 arc, pad 0)
__global__ __launch_bounds__(256) void prep_w8_kernel(const float* __restrict__ w,
                                                      const float* __restrict__ arc,
                                                      char* __restrict__ B8,
                                                      __bf16* __restrict__ Bc, int no) {
  int gid = blockIdx.x * 256 + threadIdx.x;
  int ol = gid / GRP;
  int g = gid - ol * GRP;
  if (g < 512) {
    int kk = g * 8;
    const float* wr = w + (size_t)ol * K_DIM;
    float4 v0 = *(const float4*)(wr + kk);
    float4 v1 = *(const float4*)(wr + kk + 4);
    c8 r;
    r[0] = (char)(int)rintf(v0.x * 8.0f); r[1] = (char)(int)rintf(v0.y * 8.0f);
    r[2] = (char)(int)rintf(v0.z * 8.0f); r[3] = (char)(int)rintf(v0.w * 8.0f);
    r[4] = (char)(int)rintf(v1.x * 8.0f); r[5] = (char)(int)rintf(v1.y * 8.0f);
    r[6] = (char)(int)rintf(v1.z * 8.0f); r[7] = (char)(int)rintf(v1.w * 8.0f);
    *(c8*)(B8 + (size_t)ol * K_DIM + kk) = r;
  } else {
    int j0 = (g - 512) * 8;
    bf16x8 r;
#pragma unroll
    for (int u = 0; u < 8; ++u) {
      float v = 0.f;
      int jj = j0 + u;
      if (jj < no) v = arc[(size_t)ol * no + jj];
      r[u] = (__bf16)v;
    }
    *(bf16x8*)(Bc + (size_t)ol * KO_PAD + j0) = r;
  }
}

// ---- i8 GEMM + bf16 comp: C = A8·B8^T/64 + Acomp·Bcomp^T, fp32 out.
// 256x256 tile, 512 threads (8 waves 2Mx4N, wave 128x64).
// A: LDS-staged (4 bufs x 16KB, swizzled). B: global->register, 1 tile ahead.
// Per K-tile t:
//  P0: load bF(t+1) global; BAR; lgkm0; read aH(t); 16 MFMA m0-3
//  P1: stageA(t+3); vmcnt(12); BAR [publishes A(t+1)]; lgkm0;
//      read aF(t+1); 16 MFMA m4-7
__global__ __launch_bounds__(512, 2) void gemm_i8_kernel(const char* __restrict__ A8,
                                                         const char* __restrict__ B8,
                                                         const __bf16* __restrict__ Ac,
                                                         const __bf16* __restrict__ Bc,
                                                         float* __restrict__ C) {
  __shared__ __align__(16) char ldsb[4 * 16384];  // 64 KB (A only)

  const int tid = threadIdx.x;
  const int lane = tid & 63;
  const int wid = tid >> 6;
  const int wm = (wid >> 2) * 128;  // wave M offset
  const int wn = (wid & 3) * 64;    // wave N offset

  // 2D XCD-chunked map (verified r4)
  const int x = blockIdx.x & 7;
  const int j = blockIdx.x >> 3;
  const int bm = (x & 3) * 8 + (j >> 5) * 4 + ((j >> 3) & 3);  // 0..31
  const int bn = (x >> 2) * 8 + (j & 7);                       // 0..15
  const int bmRow = bm << 8;
  const int bnRow = bn << 8;

  // A staging: thread t covers rows r0=t>>2 (+128), slot t&3; pre-swizzled
  // source k-slot ss = (t&3) ^ ((t>>3)&3). dest byte = t*16 within 8KB half.
  const int r0 = tid >> 2;
  const int ss = (tid & 3) ^ ((tid >> 3) & 3);
  const char* gA = A8 + (size_t)(bmRow + r0) * K_DIM + ss * 16;
  const char* gAc = (const char*)(Ac + (size_t)(bmRow + r0) * KO_PAD) + ss * 16;
  const char* gBc = (const char*)(Bc + (size_t)(bnRow + r0) * KO_PAD) + ss * 16;

  // A fragment reads (LDS): row = base16 + fr; k-slot lane>>4 -> lin-slot s2
  const int fr = lane & 15;
  const int s2 = (lane >> 4) ^ ((fr >> 1) & 3);
  const int aRd = (wm + fr) * 64 + s2 * 16;           // + m*1024 per m-frag
  const int bRd = 16384 + (wn + fr) * 64 + s2 * 16;   // comp section only

  // B fragment loads (GLOBAL, no swizzle): lane reads row bnRow+wn+nf*16+fr,
  // bytes [t*64 + (lane>>4)*16, +16). 16 rows x 64B segments -> L1-resident.
  const char* gBF = B8 + (size_t)(bnRow + wn + fr) * K_DIM + (lane >> 4) * 16;

  f32x4 acc[8][4] = {};  // holds i32 bits during main loop (bit_cast per MFMA)

#define MFMA_I8(M, N, AV, BV)                                                  \
  acc[M][N] = __builtin_bit_cast(f32x4, __builtin_amdgcn_mfma_i32_16x16x64_i8( \
      AV, BV, __builtin_bit_cast(i32x4, acc[M][N]), 0, 0, 0))

  auto stageA = [&](int tt) {
    const int bb = (tt & 3) * 16384;
    const size_t ke = (size_t)tt * 64;
    async16(gA + ke, (void*)(ldsb + bb + tid * 16));
    async16(gA + (size_t)128 * K_DIM + ke, (void*)(ldsb + bb + 8192 + tid * 16));
  };

  i32x4 aX[4], aY[4], bX[4], bY[4], aH[4];

  auto loadB = [&](int tt, i32x4 (&dst)[4]) {
#pragma unroll
    for (int n = 0; n < 4; ++n)
      dst[n] = *(const i32x4*)(gBF + (size_t)(n * 16) * K_DIM + tt * 64);
  };

  stageA(0); stageA(1); stageA(2);  // 6 loads
  loadB(0, bX);                     // +4 -> 10 outstanding
  // retire stageA(0): newest 8 = {stA(1)2, stA(2)2, bF(0)4}
  asm volatile("s_waitcnt vmcnt(8)" ::: "memory");
  __builtin_amdgcn_sched_barrier(0);
  __builtin_amdgcn_s_barrier();
#pragma unroll
  for (int i = 0; i < 4; ++i) aX[i] = *(const i32x4*)(ldsb + aRd + i * 1024);

  // P0(t): prefetch bF(t+1) from global; BAR; lgkm0; read aH(t); MFMA m0-3.
  auto phase0 = [&](int t, bool rdb, i32x4 (&aF)[4], i32x4 (&bF)[4],
                    i32x4 (&bFn)[4]) {
    if (rdb) loadB(t + 1, bFn);
    __builtin_amdgcn_sched_barrier(0);
    __builtin_amdgcn_s_barrier();
    asm volatile("s_waitcnt lgkmcnt(0)" ::: "memory");
    __builtin_amdgcn_sched_barrier(0);  // rule #18 fence
    const int bb = (t & 3) * 16384;
#pragma unroll
    for (int i = 0; i < 4; ++i)
      aH[i] = *(const i32x4*)(ldsb + bb + aRd + (4 + i) * 1024);
    __builtin_amdgcn_s_setprio(1);
#pragma unroll
    for (int m = 0; m < 4; ++m)
#pragma unroll
      for (int n = 0; n < 4; ++n) MFMA_I8(m, n, aF[m], bF[n]);
    __builtin_amdgcn_s_setprio(0);
    __builtin_amdgcn_sched_barrier(0);  // fence phase end
  };

  // P1(t): stageA(t+3); vmcnt(vm) [publishes A(t+1)]; BAR; lgkm0;
  // read aF(t+1); MFMA m4-7.
  auto phase1 = [&](int t, bool do_stage, int vm, bool rda, i32x4 (&bF)[4],
                    i32x4 (&aFn)[4]) {
    if (do_stage) stageA(t + 3);  // buf[(t-1)&3]: readers drained (2 BARs ago)
    if (vm == 12)      asm volatile("s_waitcnt vmcnt(12)" ::: "memory");
    else if (vm == 10) asm volatile("s_waitcnt vmcnt(10)" ::: "memory");
    else if (vm == 8)  asm volatile("s_waitcnt vmcnt(8)" ::: "memory");
    __builtin_amdgcn_sched_barrier(0);
    __builtin_amdgcn_s_barrier();  // publishes A(t+1) landed
    asm volatile("s_waitcnt lgkmcnt(0)" ::: "memory");
    __builtin_amdgcn_sched_barrier(0);  // rule #18 fence
    if (rda) {
      const int bb1 = ((t + 1) & 3) * 16384;
#pragma unroll
      for (int i = 0; i < 4; ++i)
        aFn[i] = *(const i32x4*)(ldsb + bb1 + aRd + i * 1024);
    }
    __builtin_amdgcn_s_setprio(1);
#pragma unroll
    for (int m = 0; m < 4; ++m)
#pragma unroll
      for (int n = 0; n < 4; ++n) MFMA_I8(4 + m, n, aH[m], bF[n]);
    __builtin_amdgcn_s_setprio(0);
    __builtin_amdgcn_sched_barrier(0);  // fence: reads must not sink past BAR
  };

  // steady: t=0..59 stage+vmcnt(12); tail t=60 (last stage -> stA(63)),
  // t=61 vm=10, t=62 vm=8, t=63 no publish.
  for (int t = 0; t < NT8 - 4; t += 2) {
    phase0(t, true, aX, bX, bY);
    phase1(t, true, 12, true, bX, aY);
    phase0(t + 1, true, aY, bY, bX);
    phase1(t + 1, true, 12, true, bY, aX);
  }
  phase0(NT8 - 4, true, aX, bX, bY);            // t=60: bF(61)
  phase1(NT8 - 4, true, 12, true, bX, aY);      //       stageA(63)
  phase0(NT8 - 3, true, aY, bY, bX);            // t=61: bF(62)
  phase1(NT8 - 3, false, 10, true, bY, aX);     //       publish A(62)
  phase0(NT8 - 2, true, aX, bX, bY);            // t=62: bF(63)
  phase1(NT8 - 2, false, 8, true, bX, aY);      //       publish A(63)
  phase0(NT8 - 1, false, aY, bY, bX);           // t=63
  phase1(NT8 - 1, false, -1, false, bY, aX);

  // in-place convert: acc bits are i32 sums of k_a*k_b; out_main = sum/64 (exact)
#pragma unroll
  for (int m = 0; m < 8; ++m)
#pragma unroll
    for (int n = 0; n < 4; ++n) {
      i32x4 iv = __builtin_bit_cast(i32x4, acc[m][n]);
      f32x4 fv;
#pragma unroll
      for (int jj = 0; jj < 4; ++jj) fv[jj] = (float)iv[jj] * 0.015625f;
      acc[m][n] = fv;
    }

  // ---- compensation: 8 bf16 K-tiles (K=256), single-buffer loop (A+B staged
  // at fixed offsets 0/8K/16K/24K; layout matches aRd/bRd formulas).
  for (int ct = 0; ct < NTC; ++ct) {
    const size_t ke = (size_t)ct * 64;  // 32 els * 2B
    async16(gAc + ke, (void*)(ldsb + tid * 16));
    async16(gAc + (size_t)128 * KO_PAD * 2 + ke, (void*)(ldsb + 8192 + tid * 16));
    async16(gBc + ke, (void*)(ldsb + 16384 + tid * 16));
    async16(gBc + (size_t)128 * KO_PAD * 2 + ke, (void*)(ldsb + 24576 + tid * 16));
    __syncthreads();  // drains vmcnt -> tile visible
    bf16x8 ac[8], bc[4];
#pragma unroll
    for (int m = 0; m < 8; ++m)
      ac[m] = *(const bf16x8*)(ldsb + aRd + m * 1024);
#pragma unroll
    for (int n = 0; n < 4; ++n)
      bc[n] = *(const bf16x8*)(ldsb + bRd + n * 1024);
#pragma unroll
    for (int m = 0; m < 8; ++m)
#pragma unroll
      for (int n = 0; n < 4; ++n)
        acc[m][n] = __builtin_amdgcn_mfma_f32_16x16x32_bf16(ac[m], bc[n],
                                                            acc[m][n], 0, 0, 0);
    __syncthreads();  // reads done before next stage overwrites
  }

  // C/D layout: col=lane&15, row=(lane>>4)*4+j [m89/m91; dtype-independent]
  const int cr = (lane >> 4) * 4;
  const int cc = lane & 15;
#pragma unroll
  for (int m = 0; m < 8; ++m) {
#pragma unroll
    for (int n = 0; n < 4; ++n) {
      float* cp = C + (size_t)(bmRow + wm + m * 16 + cr) * N_DIM +
                  (bnRow + wn + n * 16 + cc);
#pragma unroll
      for (int jj = 0; jj < 4; ++jj) cp[(size_t)jj * N_DIM] = acc[m][n][jj];
    }
  }
#undef MFMA_I8
}

// ================== fallback path (bf16, verified round 2) ==================
__global__ __launch_bounds__(256) void prep_x_kernel(const float* __restrict__ x,
                                                     const int* __restrict__ idx,
                                                     __bf16* __restrict__ A, int no,
                                                     int m0) {
  int gid = blockIdx.x * 256 + threadIdx.x;
  int ml = gid / (K_PAD / 8);
  int kk = (gid - ml * (K_PAD / 8)) * 8;
  const float* xr = x + (size_t)(m0 + ml) * K_DIM;
  bf16x8 r;
  if (kk < K_DIM) {
    float4 v0 = *(const float4*)(xr + kk);
    float4 v1 = *(const float4*)(xr + kk + 4);
    r[0] = qbf(v0.x); r[1] = qbf(v0.y); r[2] = qbf(v0.z); r[3] = qbf(v0.w);
    r[4] = qbf(v1.x); r[5] = qbf(v1.y); r[6] = qbf(v1.z); r[7] = qbf(v1.w);
  } else {
    int j = kk - K_DIM;
#pragma unroll
    for (int u = 0; u < 8; ++u) {
      float v = 0.f;
      int jj = j + u;
      if (jj < no) {
        float xv = xr[idx[jj]];
        v = xv - qf(xv);
      }
      r[u] = (__bf16)v;
    }
  }
  *(bf16x8*)(A + (size_t)ml * K_PAD + kk) = r;
}

__global__ __launch_bounds__(256) void prep_w_kernel(const float* __restrict__ w,
                                                     const float* __restrict__ arc,
                                                     __bf16* __restrict__ B, int no,
                                                     int n0) {
  int gid = blockIdx.x * 256 + threadIdx.x;
  int ol = gid / (K_PAD / 8);
  int kk = (gid - ol * (K_PAD / 8)) * 8;
  int o = n0 + ol;
  bf16x8 r;
  if (kk < K_DIM) {
    const float* wr = w + (size_t)o * K_DIM;
    float4 v0 = *(const float4*)(wr + kk);
    float4 v1 = *(const float4*)(wr + kk + 4);
    r[0] = qbf(v0.x); r[1] = qbf(v0.y); r[2] = qbf(v0.z); r[3] = qbf(v0.w);
    r[4] = qbf(v1.x); r[5] = qbf(v1.y); r[6] = qbf(v1.z); r[7] = qbf(v1.w);
  } else {
    int j = kk - K_DIM;
#pragma unroll
    for (int u = 0; u < 8; ++u) {
      float v = 0.f;
      int jj = j + u;
      if (jj < no) v = arc[(size_t)o * no + jj];
      r[u] = (__bf16)v;
    }
  }
  *(bf16x8*)(B + (size_t)ol * K_PAD + kk) = r;
}

__global__ __launch_bounds__(256) void gemm_bt_kernel(const __bf16* __restrict__ A,
                                                      const __bf16* __restrict__ B,
                                                      float* __restrict__ C,
                                                      int m0, int n0, int mtiles) {
  __shared__ __align__(16) __bf16 sA[128 * 64];
  __shared__ __align__(16) __bf16 sB[128 * 64];
  const int bid = blockIdx.x;
  const int bm = bid % mtiles;
  const int bn = bid / mtiles;
  const int t = threadIdx.x;
  const int lane = t & 63;
  const int w = t >> 6;
  const int wm = (w >> 1) * 64;
  const int wn = (w & 1) * 64;
  f32x4 acc[4][4] = {};
  const __bf16* gA = A + (size_t)(bm * 128 + (t >> 3)) * K_PAD + (t & 7) * 8;
  const __bf16* gB = B + (size_t)(bn * 128 + (t >> 3)) * K_PAD + (t & 7) * 8;
  char* lA = (char*)sA + t * 16;
  char* lB = (char*)sB + t * 16;
  const int fr = lane & 15;
  const int fo = (lane >> 4) * 8;
  for (int kt = 0; kt < K_PAD / 64; ++kt) {
    const int k0 = kt * 64;
#pragma unroll
    for (int i = 0; i < 4; ++i) {
      async16(gA + k0 + (size_t)i * 32 * K_PAD, lA + i * 4096);
      async16(gB + k0 + (size_t)i * 32 * K_PAD, lB + i * 4096);
    }
    __syncthreads();
#pragma unroll
    for (int kk = 0; kk < 2; ++kk) {
      bf16x8 aF[4], bF[4];
#pragma unroll
      for (int mt = 0; mt < 4; ++mt)
        aF[mt] = *(const bf16x8*)&sA[(wm + mt * 16 + fr) * 64 + kk * 32 + fo];
#pragma unroll
      for (int nt = 0; nt < 4; ++nt)
        bF[nt] = *(const bf16x8*)&sB[(wn + nt * 16 + fr) * 64 + kk * 32 + fo];
#pragma unroll
      for (int mt = 0; mt < 4; ++mt)
#pragma unroll
        for (int nt = 0; nt < 4; ++nt)
          acc[mt][nt] = __builtin_amdgcn_mfma_f32_16x16x32_bf16(
              aF[mt], bF[nt], acc[mt][nt], 0, 0, 0);
    }
    __syncthreads();
  }
  const int cr = (lane >> 4) * 4;
  const int cc = lane & 15;
#pragma unroll
  for (int mt = 0; mt < 4; ++mt)
#pragma unroll
    for (int nt = 0; nt < 4; ++nt) {
      float* cp = C + (size_t)(m0 + bm * 128 + wm + mt * 16 + cr) * N_DIM +
                  (n0 + bn * 128 + wn + nt * 16 + cc);
#pragma unroll
      for (int jj = 0; jj < 4; ++jj) cp[(size_t)jj * N_DIM] = acc[mt][nt][jj];
    }
}

__global__ __launch_bounds__(256) void naive_kernel(const float* __restrict__ x,
                                                    const float* __restrict__ w,
                                                    const float* __restrict__ arc,
                                                    const int* __restrict__ idx,
                                                    float* __restrict__ out, int no) {
  size_t gid = (size_t)blockIdx.x * 256 + threadIdx.x;
  if (gid >= (size_t)M_DIM * N_DIM) return;
  int m = (int)(gid / N_DIM), o = (int)(gid % N_DIM);
  const float* xr = x + (size_t)m * K_DIM;
  const float* wr = w + (size_t)o * K_DIM;
  float acc = 0.f;
  for (int k = 0; k < K_DIM; ++k) acc += qf(xr[k]) * qf(wr[k]);
  for (int j = 0; j < no; ++j) {
    float xv = xr[idx[j]];
    acc += (xv - qf(xv)) * arc[(size_t)o * no + j];
  }
  out[gid] = acc;
}

extern "C" void kernel_launch(void* const* d_in, const int* in_sizes, int n_in,
                              void* d_out, int out_size, void* d_ws, size_t ws_size,
                              hipStream_t stream) {
  const float* x = (const float*)d_in[0];     // (4,2048,4096)
  const float* wgt = (const float*)d_in[1];   // (4096,4096)
  const float* arc = (const float*)d_in[2];   // (4096,204)
  const int* idx = (const int*)d_in[3];       // (204,)
  float* out = (float*)d_out;                 // (4,2048,4096) fp32
  const int no = in_sizes[3];                 // 204

  const size_t FAST_WS = (size_t)M_DIM * K_DIM + (size_t)N_DIM * K_DIM +
                         (size_t)M_DIM * KO_PAD * 2 + (size_t)N_DIM * KO_PAD * 2;
  if (ws_size >= FAST_WS) {
    char* A8 = (char*)d_ws;
    char* B8 = A8 + (size_t)M_DIM * K_DIM;
    __bf16* Acp = (__bf16*)(B8 + (size_t)N_DIM * K_DIM);
    __bf16* Bcp = Acp + (size_t)M_DIM * KO_PAD;
    prep_x8_kernel<<<M_DIM * GRP / 256, 256, 0, stream>>>(x, idx, A8, Acp, no);
    prep_w8_kernel<<<N_DIM * GRP / 256, 256, 0, stream>>>(wgt, arc, B8, Bcp, no);
    gemm_i8_kernel<<<(M_DIM / 256) * (N_DIM / 256), 512, 0, stream>>>(A8, B8, Acp,
                                                                      Bcp, out);
    return;
  }

  // chunked bf16 fallback (verified round 2)
  const size_t rowb = (size_t)K_PAD * sizeof(__bf16);
  const size_t rows_avail = ws_size / rowb;
  size_t nr_c, mr_c;
  if (rows_avail >= (size_t)(N_DIM + 128)) {
    nr_c = N_DIM;
    mr_c = ((rows_avail - N_DIM) / 128) * 128;
    if (mr_c > M_DIM) mr_c = M_DIM;
  } else {
    nr_c = (rows_avail / 2 / 128) * 128;
    if (nr_c > N_DIM) nr_c = N_DIM;
    mr_c = nr_c ? (((rows_avail - nr_c) / 128) * 128) : 0;
    if (mr_c > M_DIM) mr_c = M_DIM;
  }
  if (nr_c == 0 || mr_c == 0) {
    size_t total = (size_t)M_DIM * N_DIM;
    naive_kernel<<<(int)((total + 255) / 256), 256, 0, stream>>>(x, wgt, arc, idx, out, no);
    return;
  }
  __bf16* B = (__bf16*)d_ws;
  __bf16* A = B + nr_c * (size_t)K_PAD;
  for (int n0 = 0; n0 < N_DIM; n0 += (int)nr_c) {
    const int nr = (int)((N_DIM - n0 < (int)nr_c) ? (N_DIM - n0) : (int)nr_c);
    prep_w_kernel<<<nr * (K_PAD / 8) / 256, 256, 0, stream>>>(wgt, arc, B, no, n0);
    for (int m0 = 0; m0 < M_DIM; m0 += (int)mr_c) {
      const int mr = (int)((M_DIM - m0 < (int)mr_c) ? (M_DIM - m0) : (int)mr_c);
      prep_x_kernel<<<mr * (K_PAD / 8) / 256, 256, 0, stream>>>(x, idx, A, no, m0);
      const int mtiles = mr / 128, ntiles = nr / 128;
      gemm_bt_kernel<<<mtiles * ntiles, 256, 0, stream>>>(A, B, out, m0, n0, mtiles);
    }
  }
}

// Round 15
// 224.932 us; speedup vs baseline: 1.1884x; 1.1884x over previous
//
#include <hip/hip_runtime.h>

// ARCQuantLayer: out = q(x)·q(W)^T + (x-q(x))[:,idx]·arc^T, q(v)=round(v*8)/8.
// r15: empirical law from r9-r14: tile time = MFMA + LDS bytes (pipes sum, never
// overlap). So cut LDS bytes: 4 waves x 128x128 wave-tile (acc 256 VGPR, 1
// wave/SIMD via __launch_bounds__(256,1)) -> frag reads 96->64 KB/tile.
// Schedule = r12's verified 2-phase read-ahead skeleton; swizzle/XCD map kept.
// INT8 main GEMM exact (|round(v*8)|<=~46, sums < 2^24, /64 pow2-exact).
// Comp (K=204->256) = 8 bf16 K-tiles after in-place i32->f32 convert.
// Prep fused into one kernel (x-part + w-part by block range).

#define M_DIM 8192
#define N_DIM 4096
#define K_DIM 4096
#define KO_PAD 256
#define K_PAD (K_DIM + KO_PAD)   // bf16 fallback layout
#define NT8 (K_DIM / 64)         // 64 i8 K-tiles (BK=64)
#define NTC (KO_PAD / 32)        // 8 comp bf16 K-tiles
#define GRP 544                  // prep groups/row: 512 i8 + 32 comp

typedef __bf16 bf16x8 __attribute__((ext_vector_type(8)));
typedef float f32x4 __attribute__((ext_vector_type(4)));
typedef int i32x4 __attribute__((ext_vector_type(4)));
typedef char c8 __attribute__((ext_vector_type(8)));

__device__ __forceinline__ void async16(const void* g, void* l) {
  __builtin_amdgcn_global_load_lds(
      (__attribute__((address_space(1))) void*)g,
      (__attribute__((address_space(3))) void*)l, 16, 0, 0);
}

__device__ __forceinline__ float qf(float f) { return rintf(f * 8.0f) * 0.125f; }
__device__ __forceinline__ __bf16 qbf(float f) { return (__bf16)qf(f); }

// ---- fused prep: blocks [0, xb) build A8/Ac from x; blocks [xb, ..) build B8/Bc
__global__ __launch_bounds__(256) void prep_fused_kernel(
    const float* __restrict__ x, const int* __restrict__ idx,
    const float* __restrict__ w, const float* __restrict__ arc,
    char* __restrict__ A8, __bf16* __restrict__ Ac,
    char* __restrict__ B8, __bf16* __restrict__ Bc, int no, int xb) {
  if (blockIdx.x < xb) {
    int gid = blockIdx.x * 256 + threadIdx.x;
    int ml = gid / GRP;
    int g = gid - ml * GRP;
    const float* xr = x + (size_t)ml * K_DIM;
    if (g < 512) {
      int kk = g * 8;
      float4 v0 = *(const float4*)(xr + kk);
      float4 v1 = *(const float4*)(xr + kk + 4);
      c8 r;
      r[0] = (char)(int)rintf(v0.x * 8.0f); r[1] = (char)(int)rintf(v0.y * 8.0f);
      r[2] = (char)(int)rintf(v0.z * 8.0f); r[3] = (char)(int)rintf(v0.w * 8.0f);
      r[4] = (char)(int)rintf(v1.x * 8.0f); r[5] = (char)(int)rintf(v1.y * 8.0f);
      r[6] = (char)(int)rintf(v1.z * 8.0f); r[7] = (char)(int)rintf(v1.w * 8.0f);
      *(c8*)(A8 + (size_t)ml * K_DIM + kk) = r;
    } else {
      int j0 = (g - 512) * 8;
      bf16x8 r;
#pragma unroll
      for (int u = 0; u < 8; ++u) {
        float v = 0.f;
        int jj = j0 + u;
        if (jj < no) {
          float xv = xr[idx[jj]];
          v = xv - qf(xv);
        }
        r[u] = (__bf16)v;
      }
      *(bf16x8*)(Ac + (size_t)ml * KO_PAD + j0) = r;
    }
  } else {
    int gid = (blockIdx.x - xb) * 256 + threadIdx.x;
    int ol = gid / GRP;
    int g = gid - ol * GRP;
    if (g < 512) {
      int kk = g * 8;
      const float* wr = w + (size_t)ol * K_DIM;
      float4 v0 = *(const float4*)(wr + kk);
      float4 v1 = *(const float4*)(wr + kk + 4);
      c8 r;
      r[0] = (char)(int)rintf(v0.x * 8.0f); r[1] = (char)(int)rintf(v0.y * 8.0f);
      r[2] = (char)(int)rintf(v0.z * 8.0f); r[3] = (char)(int)rintf(v0.w * 8.0f);
      r[4] = (char)(int)rintf(v1.x * 8.0f); r[5] = (char)(int)rintf(v1.y * 8.0f);
      r[6] = (char)(int)rintf(v1.z * 8.0f); r[7] = (char)(int)rintf(v1.w * 8.0f);
      *(c8*)(B8 + (size_t)ol * K_DIM + kk) = r;
    } else {
      int j0 = (g - 512) * 8;
      bf16x8 r;
#pragma unroll
      for (int u = 0; u < 8; ++u) {
        float v = 0.f;
        int jj = j0 + u;
        if (jj < no) v = arc[(size_t)ol * no + jj];
        r[u] = (__bf16)v;
      }
      *(bf16x8*)(Bc + (size_t)ol * KO_PAD + j0) = r;
    }
  }
}

// ---- i8 GEMM + bf16 comp: C = A8·B8^T/64 + Acomp·Bcomp^T, fp32 out.
// 256x256 tile, 256 threads (4 waves 2x2, wave 128x128), 4 LDS bufs x 32KB.
// Per K-tile t (r12 skeleton, read-ahead one phase):
//  P0: BAR; lgkm0; read aH(t) m4-7; 32 MFMA m0-3 x n0-7
//  P1: stage(t+3); vmcnt(16); BAR [publishes t+1]; lgkm0;
//      read aF(t+1) m0-3 + bF(t+1) n0-7; 32 MFMA m4-7 x n0-7
__global__ __launch_bounds__(256, 1) void gemm_i8_kernel(const char* __restrict__ A8,
                                                         const char* __restrict__ B8,
                                                         const __bf16* __restrict__ Ac,
                                                         const __bf16* __restrict__ Bc,
                                                         float* __restrict__ C) {
  __shared__ __align__(16) char ldsb[4 * 32768];  // 128 KB

  const int tid = threadIdx.x;
  const int lane = tid & 63;
  const int wid = tid >> 6;
  const int wm = (wid >> 1) * 128;  // wave M offset
  const int wn = (wid & 1) * 128;   // wave N offset

  // 2D XCD-chunked map (verified r4)
  const int x = blockIdx.x & 7;
  const int j = blockIdx.x >> 3;
  const int bm = (x & 3) * 8 + (j >> 5) * 4 + ((j >> 3) & 3);  // 0..31
  const int bn = (x >> 2) * 8 + (j & 7);                       // 0..15
  const int bmRow = bm << 8;
  const int bnRow = bn << 8;

  // staging: thread t covers rows r0=t>>2 (+64k, k=0..3), slot t&3; pre-swizzled
  // source k-slot ss = (t&3) ^ ((r0>>1)&3) = (t&3) ^ ((t>>3)&3). dest = k*4096+t*16.
  const int r0 = tid >> 2;
  const int ss = (tid & 3) ^ ((tid >> 3) & 3);
  const char* gA = A8 + (size_t)(bmRow + r0) * K_DIM + ss * 16;
  const char* gB = B8 + (size_t)(bnRow + r0) * K_DIM + ss * 16;
  const char* gAc = (const char*)(Ac + (size_t)(bmRow + r0) * KO_PAD) + ss * 16;
  const char* gBc = (const char*)(Bc + (size_t)(bnRow + r0) * KO_PAD) + ss * 16;

  // fragment reads: row = base16 + fr; want k-slot lane>>4 -> lin-slot s2
  const int fr = lane & 15;
  const int s2 = (lane >> 4) ^ ((fr >> 1) & 3);
  const int aRd = (wm + fr) * 64 + s2 * 16;           // + m*1024, m=0..7
  const int bRd = 16384 + (wn + fr) * 64 + s2 * 16;   // + n*1024, n=0..7

  f32x4 acc[8][8] = {};  // holds i32 bits during main loop (bit_cast per MFMA)

#define MFMA_I8(M, N, AV, BV)                                                  \
  acc[M][N] = __builtin_bit_cast(f32x4, __builtin_amdgcn_mfma_i32_16x16x64_i8( \
      AV, BV, __builtin_bit_cast(i32x4, acc[M][N]), 0, 0, 0))

  auto stage = [&](int tt) {
    const int bb = (tt & 3) * 32768;
    const size_t ke = (size_t)tt * 64;
#pragma unroll
    for (int k = 0; k < 4; ++k) {
      async16(gA + (size_t)(64 * k) * K_DIM + ke,
              (void*)(ldsb + bb + k * 4096 + tid * 16));
      async16(gB + (size_t)(64 * k) * K_DIM + ke,
              (void*)(ldsb + bb + 16384 + k * 4096 + tid * 16));
    }
  };

  stage(0); stage(1); stage(2);  // 24 loads

  // retire stage(0): leave newest 16 = {stage(1), stage(2)}
  asm volatile("s_waitcnt vmcnt(16)" ::: "memory");
  __builtin_amdgcn_sched_barrier(0);
  __builtin_amdgcn_s_barrier();

  i32x4 aX[4], aY[4], aH[4], bX[8], bY[8];
#pragma unroll
  for (int i = 0; i < 4; ++i) aX[i] = *(const i32x4*)(ldsb + aRd + i * 1024);
#pragma unroll
  for (int n = 0; n < 8; ++n) bX[n] = *(const i32x4*)(ldsb + bRd + n * 1024);

  // P0(t): read aH(t); MFMA m0-3 x n0-7 (operands read last phase).
  auto phase0 = [&](int t, i32x4 (&aF)[4], i32x4 (&bF)[8]) {
    __builtin_amdgcn_s_barrier();
    asm volatile("s_waitcnt lgkmcnt(0)" ::: "memory");
    __builtin_amdgcn_sched_barrier(0);  // rule #18 fence
    const int bb = (t & 3) * 32768;
#pragma unroll
    for (int i = 0; i < 4; ++i)
      aH[i] = *(const i32x4*)(ldsb + bb + aRd + (4 + i) * 1024);
    __builtin_amdgcn_s_setprio(1);
#pragma unroll
    for (int m = 0; m < 4; ++m)
#pragma unroll
      for (int n = 0; n < 8; ++n) MFMA_I8(m, n, aF[m], bF[n]);
    __builtin_amdgcn_s_setprio(0);
    __builtin_amdgcn_sched_barrier(0);  // fence phase end
  };

  // P1(t): stage(t+3); publish t+1; read t+1 frags; MFMA m4-7 x n0-7.
  auto phase1 = [&](int t, bool do_stage, int vm, bool rd, i32x4 (&bF)[8],
                    i32x4 (&aFn)[4], i32x4 (&bFn)[8]) {
    if (do_stage) stage(t + 3);  // buf[(t-1)&3]: its readers drained >=2 BARs ago
    if (vm == 16)     asm volatile("s_waitcnt vmcnt(16)" ::: "memory");
    else if (vm == 8) asm volatile("s_waitcnt vmcnt(8)" ::: "memory");
    else if (vm == 0) asm volatile("s_waitcnt vmcnt(0)" ::: "memory");
    __builtin_amdgcn_sched_barrier(0);
    __builtin_amdgcn_s_barrier();  // publishes tile t+1 landed
    asm volatile("s_waitcnt lgkmcnt(0)" ::: "memory");
    __builtin_amdgcn_sched_barrier(0);  // rule #18 fence
    if (rd) {
      const int bb1 = ((t + 1) & 3) * 32768;
#pragma unroll
      for (int i = 0; i < 4; ++i)
        aFn[i] = *(const i32x4*)(ldsb + bb1 + aRd + i * 1024);
#pragma unroll
      for (int n = 0; n < 8; ++n)
        bFn[n] = *(const i32x4*)(ldsb + bb1 + bRd + n * 1024);
    }
    __builtin_amdgcn_s_setprio(1);
#pragma unroll
    for (int m = 0; m < 4; ++m)
#pragma unroll
      for (int n = 0; n < 8; ++n) MFMA_I8(4 + m, n, aH[m], bF[n]);
    __builtin_amdgcn_s_setprio(0);
    __builtin_amdgcn_sched_barrier(0);  // fence: reads must not sink past BAR
  };

  for (int t = 0; t < NT8 - 4; t += 2) {
    phase0(t, aX, bX);
    phase1(t, true, 16, true, bX, aY, bY);
    phase0(t + 1, aY, bY);
    phase1(t + 1, true, 16, true, bY, aX, bX);
  }
  phase0(NT8 - 4, aX, bX);                       // t=60
  phase1(NT8 - 4, true, 16, true, bX, aY, bY);   //   stage(63), publish 61
  phase0(NT8 - 3, aY, bY);                       // t=61
  phase1(NT8 - 3, false, 8, true, bY, aX, bX);   //   publish 62
  phase0(NT8 - 2, aX, bX);                       // t=62
  phase1(NT8 - 2, false, 0, true, bX, aY, bY);   //   publish 63
  phase0(NT8 - 1, aY, bY);                       // t=63
  phase1(NT8 - 1, false, -1, false, bY, aX, bX);

  // in-place convert: acc bits are i32 sums of k_a*k_b; out_main = sum/64 (exact)
#pragma unroll
  for (int m = 0; m < 8; ++m)
#pragma unroll
    for (int n = 0; n < 8; ++n) {
      i32x4 iv = __builtin_bit_cast(i32x4, acc[m][n]);
      f32x4 fv;
#pragma unroll
      for (int jj = 0; jj < 4; ++jj) fv[jj] = (float)iv[jj] * 0.015625f;
      acc[m][n] = fv;
    }

  // ---- compensation: 8 bf16 K-tiles (K=256), single-buffer loop.
  // Layout matches aRd/bRd (64B rows: 32 bf16). A at 0, B at 16384.
  for (int ct = 0; ct < NTC; ++ct) {
    const size_t ke = (size_t)ct * 64;  // 32 els * 2B
#pragma unroll
    for (int k = 0; k < 4; ++k) {
      async16(gAc + (size_t)(64 * k) * 512 + ke,
              (void*)(ldsb + k * 4096 + tid * 16));
      async16(gBc + (size_t)(64 * k) * 512 + ke,
              (void*)(ldsb + 16384 + k * 4096 + tid * 16));
    }
    __syncthreads();  // drains vmcnt -> tile visible
    bf16x8 ac[8], bc[8];
#pragma unroll
    for (int m = 0; m < 8; ++m)
      ac[m] = *(const bf16x8*)(ldsb + aRd + m * 1024);
#pragma unroll
    for (int n = 0; n < 8; ++n)
      bc[n] = *(const bf16x8*)(ldsb + bRd + n * 1024);
#pragma unroll
    for (int m = 0; m < 8; ++m)
#pragma unroll
      for (int n = 0; n < 8; ++n)
        acc[m][n] = __builtin_amdgcn_mfma_f32_16x16x32_bf16(ac[m], bc[n],
                                                            acc[m][n], 0, 0, 0);
    __syncthreads();  // reads done before next stage overwrites
  }

  // C/D layout: col=lane&15, row=(lane>>4)*4+j [m89/m91; dtype-independent]
  const int cr = (lane >> 4) * 4;
  const int cc = lane & 15;
#pragma unroll
  for (int m = 0; m < 8; ++m) {
#pragma unroll
    for (int n = 0; n < 8; ++n) {
      float* cp = C + (size_t)(bmRow + wm + m * 16 + cr) * N_DIM +
                  (bnRow + wn + n * 16 + cc);
#pragma unroll
      for (int jj = 0; jj < 4; ++jj) cp[(size_t)jj * N_DIM] = acc[m][n][jj];
    }
  }
#undef MFMA_I8
}

// ================== fallback path (bf16, verified round 2) ==================
__global__ __launch_bounds__(256) void prep_x_kernel(const float* __restrict__ x,
                                                     const int* __restrict__ idx,
                                                     __bf16* __restrict__ A, int no,
                                                     int m0) {
  int gid = blockIdx.x * 256 + threadIdx.x;
  int ml = gid / (K_PAD / 8);
  int kk = (gid - ml * (K_PAD / 8)) * 8;
  const float* xr = x + (size_t)(m0 + ml) * K_DIM;
  bf16x8 r;
  if (kk < K_DIM) {
    float4 v0 = *(const float4*)(xr + kk);
    float4 v1 = *(const float4*)(xr + kk + 4);
    r[0] = qbf(v0.x); r[1] = qbf(v0.y); r[2] = qbf(v0.z); r[3] = qbf(v0.w);
    r[4] = qbf(v1.x); r[5] = qbf(v1.y); r[6] = qbf(v1.z); r[7] = qbf(v1.w);
  } else {
    int j = kk - K_DIM;
#pragma unroll
    for (int u = 0; u < 8; ++u) {
      float v = 0.f;
      int jj = j + u;
      if (jj < no) {
        float xv = xr[idx[jj]];
        v = xv - qf(xv);
      }
      r[u] = (__bf16)v;
    }
  }
  *(bf16x8*)(A + (size_t)ml * K_PAD + kk) = r;
}

__global__ __launch_bounds__(256) void prep_w_kernel(const float* __restrict__ w,
                                                     const float* __restrict__ arc,
                                                     __bf16* __restrict__ B, int no,
                                                     int n0) {
  int gid = blockIdx.x * 256 + threadIdx.x;
  int ol = gid / (K_PAD / 8);
  int kk = (gid - ol * (K_PAD / 8)) * 8;
  int o = n0 + ol;
  bf16x8 r;
  if (kk < K_DIM) {
    const float* wr = w + (size_t)o * K_DIM;
    float4 v0 = *(const float4*)(wr + kk);
    float4 v1 = *(const float4*)(wr + kk + 4);
    r[0] = qbf(v0.x); r[1] = qbf(v0.y); r[2] = qbf(v0.z); r[3] = qbf(v0.w);
    r[4] = qbf(v1.x); r[5] = qbf(v1.y); r[6] = qbf(v1.z); r[7] = qbf(v1.w);
  } else {
    int j = kk - K_DIM;
#pragma unroll
    for (int u = 0; u < 8; ++u) {
      float v = 0.f;
      int jj = j + u;
      if (jj < no) v = arc[(size_t)o * no + jj];
      r[u] = (__bf16)v;
    }
  }
  *(bf16x8*)(B + (size_t)ol * K_PAD + kk) = r;
}

__global__ __launch_bounds__(256) void gemm_bt_kernel(const __bf16* __restrict__ A,
                                                      const __bf16* __restrict__ B,
                                                      float* __restrict__ C,
                                                      int m0, int n0, int mtiles) {
  __shared__ __align__(16) __bf16 sA[128 * 64];
  __shared__ __align__(16) __bf16 sB[128 * 64];
  const int bid = blockIdx.x;
  const int bm = bid % mtiles;
  const int bn = bid / mtiles;
  const int t = threadIdx.x;
  const int lane = t & 63;
  const int w = t >> 6;
  const int wm = (w >> 1) * 64;
  const int wn = (w & 1) * 64;
  f32x4 acc[4][4] = {};
  const __bf16* gA = A + (size_t)(bm * 128 + (t >> 3)) * K_PAD + (t & 7) * 8;
  const __bf16* gB = B + (size_t)(bn * 128 + (t >> 3)) * K_PAD + (t & 7) * 8;
  char* lA = (char*)sA + t * 16;
  char* lB = (char*)sB + t * 16;
  const int fr = lane & 15;
  const int fo = (lane >> 4) * 8;
  for (int kt = 0; kt < K_PAD / 64; ++kt) {
    const int k0 = kt * 64;
#pragma unroll
    for (int i = 0; i < 4; ++i) {
      async16(gA + k0 + (size_t)i * 32 * K_PAD, lA + i * 4096);
      async16(gB + k0 + (size_t)i * 32 * K_PAD, lB + i * 4096);
    }
    __syncthreads();
#pragma unroll
    for (int kk = 0; kk < 2; ++kk) {
      bf16x8 aF[4], bF[4];
#pragma unroll
      for (int mt = 0; mt < 4; ++mt)
        aF[mt] = *(const bf16x8*)&sA[(wm + mt * 16 + fr) * 64 + kk * 32 + fo];
#pragma unroll
      for (int nt = 0; nt < 4; ++nt)
        bF[nt] = *(const bf16x8*)&sB[(wn + nt * 16 + fr) * 64 + kk * 32 + fo];
#pragma unroll
      for (int mt = 0; mt < 4; ++mt)
#pragma unroll
        for (int nt = 0; nt < 4; ++nt)
          acc[mt][nt] = __builtin_amdgcn_mfma_f32_16x16x32_bf16(
              aF[mt], bF[nt], acc[mt][nt], 0, 0, 0);
    }
    __syncthreads();
  }
  const int cr = (lane >> 4) * 4;
  const int cc = lane & 15;
#pragma unroll
  for (int mt = 0; mt < 4; ++mt)
#pragma unroll
    for (int nt = 0; nt < 4; ++nt) {
      float* cp = C + (size_t)(m0 + bm * 128 + wm + mt * 16 + cr) * N_DIM +
                  (n0 + bn * 128 + wn + nt * 16 + cc);
#pragma unroll
      for (int jj = 0; jj < 4; ++jj) cp[(size_t)jj * N_DIM] = acc[mt][nt][jj];
    }
}

__global__ __launch_bounds__(256) void naive_kernel(const float* __restrict__ x,
                                                    const float* __restrict__ w,
                                                    const float* __restrict__ arc,
                                                    const int* __restrict__ idx,
                                                    float* __restrict__ out, int no) {
  size_t gid = (size_t)blockIdx.x * 256 + threadIdx.x;
  if (gid >= (size_t)M_DIM * N_DIM) return;
  int m = (int)(gid / N_DIM), o = (int)(gid % N_DIM);
  const float* xr = x + (size_t)m * K_DIM;
  const float* wr = w + (size_t)o * K_DIM;
  float acc = 0.f;
  for (int k = 0; k < K_DIM; ++k) acc += qf(xr[k]) * qf(wr[k]);
  for (int j = 0; j < no; ++j) {
    float xv = xr[idx[j]];
    acc += (xv - qf(xv)) * arc[(size_t)o * no + j];
  }
  out[gid] = acc;
}

extern "C" void kernel_launch(void* const* d_in, const int* in_sizes, int n_in,
                              void* d_out, int out_size, void* d_ws, size_t ws_size,
                              hipStream_t stream) {
  const float* x = (const float*)d_in[0];     // (4,2048,4096)
  const float* wgt = (const float*)d_in[1];   // (4096,4096)
  const float* arc = (const float*)d_in[2];   // (4096,204)
  const int* idx = (const int*)d_in[3];       // (204,)
  float* out = (float*)d_out;                 // (4,2048,4096) fp32
  const int no = in_sizes[3];                 // 204

  const size_t FAST_WS = (size_t)M_DIM * K_DIM + (size_t)N_DIM * K_DIM +
                         (size_t)M_DIM * KO_PAD * 2 + (size_t)N_DIM * KO_PAD * 2;
  if (ws_size >= FAST_WS) {
    char* A8 = (char*)d_ws;
    char* B8 = A8 + (size_t)M_DIM * K_DIM;
    __bf16* Acp = (__bf16*)(B8 + (size_t)N_DIM * K_DIM);
    __bf16* Bcp = Acp + (size_t)M_DIM * KO_PAD;
    const int xb = M_DIM * GRP / 256;         // 17408 x-blocks
    const int wb = N_DIM * GRP / 256;         // 8704 w-blocks
    prep_fused_kernel<<<xb + wb, 256, 0, stream>>>(x, idx, wgt, arc, A8, Acp, B8,
                                                   Bcp, no, xb);
    gemm_i8_kernel<<<(M_DIM / 256) * (N_DIM / 256), 256, 0, stream>>>(A8, B8, Acp,
                                                                      Bcp, out);
    return;
  }

  // chunked bf16 fallback (verified round 2)
  const size_t rowb = (size_t)K_PAD * sizeof(__bf16);
  const size_t rows_avail = ws_size / rowb;
  size_t nr_c, mr_c;
  if (rows_avail >= (size_t)(N_DIM + 128)) {
    nr_c = N_DIM;
    mr_c = ((rows_avail - N_DIM) / 128) * 128;
    if (mr_c > M_DIM) mr_c = M_DIM;
  } else {
    nr_c = (rows_avail / 2 / 128) * 128;
    if (nr_c > N_DIM) nr_c = N_DIM;
    mr_c = nr_c ? (((rows_avail - nr_c) / 128) * 128) : 0;
    if (mr_c > M_DIM) mr_c = M_DIM;
  }
  if (nr_c == 0 || mr_c == 0) {
    size_t total = (size_t)M_DIM * N_DIM;
    naive_kernel<<<(int)((total + 255) / 256), 256, 0, stream>>>(x, wgt, arc, idx, out, no);
    return;
  }
  __bf16* B = (__bf16*)d_ws;
  __bf16* A = B + nr_c * (size_t)K_PAD;
  for (int n0 = 0; n0 < N_DIM; n0 += (int)nr_c) {
    const int nr = (int)((N_DIM - n0 < (int)nr_c) ? (N_DIM - n0) : (int)nr_c);
    prep_w_kernel<<<nr * (K_PAD / 8) / 256, 256, 0, stream>>>(wgt, arc, B, no, n0);
    for (int m0 = 0; m0 < M_DIM; m0 += (int)mr_c) {
      const int mr = (int)((M_DIM - m0 < (int)mr_c) ? (M_DIM - m0) : (int)mr_c);
      prep_x_kernel<<<mr * (K_PAD / 8) / 256, 256, 0, stream>>>(x, idx, A, no, m0);
      const int mtiles = mr / 128, ntiles = nr / 128;
      gemm_bt_kernel<<<mtiles * ntiles, 256, 0, stream>>>(A, B, out, m0, n0, mtiles);
    }
  }
}

// Round 16
// 194.813 us; speedup vs baseline: 1.3721x; 1.1546x over previous
//
#include <hip/hip_runtime.h>

// ARCQuantLayer: out = q(x)·q(W)^T + (x-q(x))[:,idx]·arc^T, q(v)=round(v*8)/8.
// r16 = r12 GEMM (best: 147us, 46% MfmaUtil; wave 128x64 @ 2 waves/SIMD proved
// optimal over r8/r10/r13/r14/r15 variants) + r15's fused one-launch prep
// (saves ~20us of launch/serialization vs two prep kernels).
// INT8 main GEMM exact (|round(v*8)|<=~46, sums < 2^24, /64 pow2-exact).
// Comp (K=204->256) = 8 bf16 K-tiles after in-place i32->f32 convert.

#define M_DIM 8192
#define N_DIM 4096
#define K_DIM 4096
#define KO_PAD 256
#define K_PAD (K_DIM + KO_PAD)   // bf16 fallback layout
#define NT8 (K_DIM / 64)         // 64 i8 K-tiles (BK=64)
#define NTC (KO_PAD / 32)        // 8 comp bf16 K-tiles
#define GRP 544                  // prep groups/row: 512 i8 + 32 comp

typedef __bf16 bf16x8 __attribute__((ext_vector_type(8)));
typedef float f32x4 __attribute__((ext_vector_type(4)));
typedef int i32x4 __attribute__((ext_vector_type(4)));
typedef char c8 __attribute__((ext_vector_type(8)));

__device__ __forceinline__ void async16(const void* g, void* l) {
  __builtin_amdgcn_global_load_lds(
      (__attribute__((address_space(1))) void*)g,
      (__attribute__((address_space(3))) void*)l, 16, 0, 0);
}

__device__ __forceinline__ float qf(float f) { return rintf(f * 8.0f) * 0.125f; }
__device__ __forceinline__ __bf16 qbf(float f) { return (__bf16)qf(f); }

// ---- fused prep: blocks [0, xb) build A8/Ac from x; blocks [xb, ..) build B8/Bc
__global__ __launch_bounds__(256) void prep_fused_kernel(
    const float* __restrict__ x, const int* __restrict__ idx,
    const float* __restrict__ w, const float* __restrict__ arc,
    char* __restrict__ A8, __bf16* __restrict__ Ac,
    char* __restrict__ B8, __bf16* __restrict__ Bc, int no, int xb) {
  if (blockIdx.x < xb) {
    int gid = blockIdx.x * 256 + threadIdx.x;
    int ml = gid / GRP;
    int g = gid - ml * GRP;
    const float* xr = x + (size_t)ml * K_DIM;
    if (g < 512) {
      int kk = g * 8;
      float4 v0 = *(const float4*)(xr + kk);
      float4 v1 = *(const float4*)(xr + kk + 4);
      c8 r;
      r[0] = (char)(int)rintf(v0.x * 8.0f); r[1] = (char)(int)rintf(v0.y * 8.0f);
      r[2] = (char)(int)rintf(v0.z * 8.0f); r[3] = (char)(int)rintf(v0.w * 8.0f);
      r[4] = (char)(int)rintf(v1.x * 8.0f); r[5] = (char)(int)rintf(v1.y * 8.0f);
      r[6] = (char)(int)rintf(v1.z * 8.0f); r[7] = (char)(int)rintf(v1.w * 8.0f);
      *(c8*)(A8 + (size_t)ml * K_DIM + kk) = r;
    } else {
      int j0 = (g - 512) * 8;
      bf16x8 r;
#pragma unroll
      for (int u = 0; u < 8; ++u) {
        float v = 0.f;
        int jj = j0 + u;
        if (jj < no) {
          float xv = xr[idx[jj]];
          v = xv - qf(xv);
        }
        r[u] = (__bf16)v;
      }
      *(bf16x8*)(Ac + (size_t)ml * KO_PAD + j0) = r;
    }
  } else {
    int gid = (blockIdx.x - xb) * 256 + threadIdx.x;
    int ol = gid / GRP;
    int g = gid - ol * GRP;
    if (g < 512) {
      int kk = g * 8;
      const float* wr = w + (size_t)ol * K_DIM;
      float4 v0 = *(const float4*)(wr + kk);
      float4 v1 = *(const float4*)(wr + kk + 4);
      c8 r;
      r[0] = (char)(int)rintf(v0.x * 8.0f); r[1] = (char)(int)rintf(v0.y * 8.0f);
      r[2] = (char)(int)rintf(v0.z * 8.0f); r[3] = (char)(int)rintf(v0.w * 8.0f);
      r[4] = (char)(int)rintf(v1.x * 8.0f); r[5] = (char)(int)rintf(v1.y * 8.0f);
      r[6] = (char)(int)rintf(v1.z * 8.0f); r[7] = (char)(int)rintf(v1.w * 8.0f);
      *(c8*)(B8 + (size_t)ol * K_DIM + kk) = r;
    } else {
      int j0 = (g - 512) * 8;
      bf16x8 r;
#pragma unroll
      for (int u = 0; u < 8; ++u) {
        float v = 0.f;
        int jj = j0 + u;
        if (jj < no) v = arc[(size_t)ol * no + jj];
        r[u] = (__bf16)v;
      }
      *(bf16x8*)(Bc + (size_t)ol * KO_PAD + j0) = r;
    }
  }
}

// ---- i8 GEMM + bf16 comp: C = A8·B8^T/64 + Acomp·Bcomp^T, fp32 out.
// 256x256 tile, 512 threads (8 waves 2Mx4N, wave 128x64), 4 LDS bufs x 32KB.
// Per K-tile t (r12, verified 147us):
//  P0: stageA(t+3); BAR; lgkm0; {1 aH read, 4 MFMA m0-3} x4 (SGB-pinned)
//  P1: stageB(t+3); vmcnt(8); BAR [publishes t+1]; lgkm0;
//      {2 reads aF/bF(t+1), 4 MFMA m4-7} x4 (SGB-pinned)
__global__ __launch_bounds__(512, 2) void gemm_i8_kernel(const char* __restrict__ A8,
                                                         const char* __restrict__ B8,
                                                         const __bf16* __restrict__ Ac,
                                                         const __bf16* __restrict__ Bc,
                                                         float* __restrict__ C) {
  __shared__ __align__(16) char ldsb[4 * 32768];  // 128 KB

  const int tid = threadIdx.x;
  const int lane = tid & 63;
  const int wid = tid >> 6;
  const int wm = (wid >> 2) * 128;  // wave M offset
  const int wn = (wid & 3) * 64;    // wave N offset

  // 2D XCD-chunked map (verified r4)
  const int x = blockIdx.x & 7;
  const int j = blockIdx.x >> 3;
  const int bm = (x & 3) * 8 + (j >> 5) * 4 + ((j >> 3) & 3);  // 0..31
  const int bn = (x >> 2) * 8 + (j & 7);                       // 0..15
  const int bmRow = bm << 8;
  const int bnRow = bn << 8;

  // staging: thread t covers rows r0=t>>2 (+128), slot t&3; pre-swizzled source
  // k-slot ss = (t&3) ^ ((r0>>1)&3) = (t&3) ^ ((t>>3)&3). dest byte = t*16.
  const int r0 = tid >> 2;
  const int ss = (tid & 3) ^ ((tid >> 3) & 3);
  const char* gA = A8 + (size_t)(bmRow + r0) * K_DIM + ss * 16;
  const char* gB = B8 + (size_t)(bnRow + r0) * K_DIM + ss * 16;
  const char* gAc = (const char*)(Ac + (size_t)(bmRow + r0) * KO_PAD) + ss * 16;
  const char* gBc = (const char*)(Bc + (size_t)(bnRow + r0) * KO_PAD) + ss * 16;

  // fragment reads: row = base16 + fr; want k-slot lane>>4 -> lin-slot s2
  const int fr = lane & 15;
  const int s2 = (lane >> 4) ^ ((fr >> 1) & 3);
  const int aRd = (wm + fr) * 64 + s2 * 16;           // + m*1024 per m-frag
  const int bRd = 16384 + (wn + fr) * 64 + s2 * 16;   // + n*1024 per n-frag

  f32x4 acc[8][4] = {};  // holds i32 bits during main loop (bit_cast per MFMA)

#define MFMA_I8(M, N, AV, BV)                                                  \
  acc[M][N] = __builtin_bit_cast(f32x4, __builtin_amdgcn_mfma_i32_16x16x64_i8( \
      AV, BV, __builtin_bit_cast(i32x4, acc[M][N]), 0, 0, 0))

  auto stageA = [&](int tt) {
    const int bb = (tt & 3) * 32768;
    const size_t ke = (size_t)tt * 64;
    async16(gA + ke, (void*)(ldsb + bb + tid * 16));
    async16(gA + (size_t)128 * K_DIM + ke, (void*)(ldsb + bb + 8192 + tid * 16));
  };
  auto stageB = [&](int tt) {
    const int bb = (tt & 3) * 32768;
    const size_t ke = (size_t)tt * 64;
    async16(gB + ke, (void*)(ldsb + bb + 16384 + tid * 16));
    async16(gB + (size_t)128 * K_DIM + ke, (void*)(ldsb + bb + 24576 + tid * 16));
  };

  stageA(0); stageB(0);
  stageA(1); stageB(1);
  stageA(2); stageB(2);

  // prologue: 12 loads out -> vmcnt(8) retires tile0; BAR publishes; preload.
  asm volatile("s_waitcnt vmcnt(8)" ::: "memory");
  __builtin_amdgcn_sched_barrier(0);
  __builtin_amdgcn_s_barrier();

  i32x4 aX[4], bX[4], aY[4], bY[4], aH[4];
#pragma unroll
  for (int i = 0; i < 4; ++i) aX[i] = *(const i32x4*)(ldsb + aRd + i * 1024);
#pragma unroll
  for (int n = 0; n < 4; ++n) bX[n] = *(const i32x4*)(ldsb + bRd + n * 1024);

  // P0(t): {1 aH read + 4 MFMA} x4, SGB-pinned interleave.
  auto phase0 = [&](int t, bool do_stage, i32x4 (&aF)[4], i32x4 (&bF)[4]) {
    if (do_stage) stageA(t + 3);
    __builtin_amdgcn_s_barrier();
    asm volatile("s_waitcnt lgkmcnt(0)" ::: "memory");
    __builtin_amdgcn_sched_barrier(0);  // rule #18 fence
    const int bb = (t & 3) * 32768;
    __builtin_amdgcn_s_setprio(1);
#pragma unroll
    for (int i = 0; i < 4; ++i) {
      aH[i] = *(const i32x4*)(ldsb + bb + aRd + (4 + i) * 1024);
#pragma unroll
      for (int n = 0; n < 4; ++n) MFMA_I8(i, n, aF[i], bF[n]);
    }
#pragma unroll
    for (int g = 0; g < 4; ++g) {
      __builtin_amdgcn_sched_group_barrier(0x100, 1, 0);  // 1 DS_READ
      __builtin_amdgcn_sched_group_barrier(0x008, 4, 0);  // 4 MFMA
    }
    __builtin_amdgcn_s_setprio(0);
    __builtin_amdgcn_sched_barrier(0);  // fence phase end
  };

  // P1(t): publish t+1; {2 reads (t+1 frags) + 4 MFMA m4-7} x4, SGB-pinned.
  auto phase1 = [&](int t, bool do_stage, int vm, bool rd, i32x4 (&bF)[4],
                    i32x4 (&aFn)[4], i32x4 (&bFn)[4]) {
    if (do_stage) stageB(t + 3);
    if (vm == 8)      asm volatile("s_waitcnt vmcnt(8)" ::: "memory");
    else if (vm == 4) asm volatile("s_waitcnt vmcnt(4)" ::: "memory");
    else if (vm == 0) asm volatile("s_waitcnt vmcnt(0)" ::: "memory");
    __builtin_amdgcn_sched_barrier(0);
    __builtin_amdgcn_s_barrier();  // publishes tile t+1 landed
    asm volatile("s_waitcnt lgkmcnt(0)" ::: "memory");
    __builtin_amdgcn_sched_barrier(0);  // rule #18 fence
    __builtin_amdgcn_s_setprio(1);
    if (rd) {
      const int bb1 = ((t + 1) & 3) * 32768;
#pragma unroll
      for (int i = 0; i < 4; ++i) {
        aFn[i] = *(const i32x4*)(ldsb + bb1 + aRd + i * 1024);
        bFn[i] = *(const i32x4*)(ldsb + bb1 + bRd + i * 1024);
#pragma unroll
        for (int n = 0; n < 4; ++n) MFMA_I8(4 + i, n, aH[i], bF[n]);
      }
#pragma unroll
      for (int g = 0; g < 4; ++g) {
        __builtin_amdgcn_sched_group_barrier(0x100, 2, 0);  // 2 DS_READ
        __builtin_amdgcn_sched_group_barrier(0x008, 4, 0);  // 4 MFMA
      }
    } else {
#pragma unroll
      for (int i = 0; i < 4; ++i)
#pragma unroll
        for (int n = 0; n < 4; ++n) MFMA_I8(4 + i, n, aH[i], bF[n]);
    }
    __builtin_amdgcn_s_setprio(0);
    __builtin_amdgcn_sched_barrier(0);  // fence: reads must not sink past BAR
  };

  for (int t = 0; t < NT8 - 4; t += 2) {
    phase0(t, true, aX, bX);
    phase1(t, true, 8, true, bX, aY, bY);
    phase0(t + 1, true, aY, bY);
    phase1(t + 1, true, 8, true, bY, aX, bX);
  }
  phase0(NT8 - 4, true, aX, bX);                // t=60: stageA(63)
  phase1(NT8 - 4, true, 8, true, bX, aY, bY);   //       stageB(63), publish 61
  phase0(NT8 - 3, false, aY, bY);               // t=61
  phase1(NT8 - 3, false, 4, true, bY, aX, bX);  //       publish 62
  phase0(NT8 - 2, false, aX, bX);               // t=62
  phase1(NT8 - 2, false, 0, true, bX, aY, bY);  //       publish 63
  phase0(NT8 - 1, false, aY, bY);               // t=63
  phase1(NT8 - 1, false, -1, false, bY, aX, bX);

  // in-place convert: acc bits are i32 sums of k_a*k_b; out_main = sum/64 (exact)
#pragma unroll
  for (int m = 0; m < 8; ++m)
#pragma unroll
    for (int n = 0; n < 4; ++n) {
      i32x4 iv = __builtin_bit_cast(i32x4, acc[m][n]);
      f32x4 fv;
#pragma unroll
      for (int jj = 0; jj < 4; ++jj) fv[jj] = (float)iv[jj] * 0.015625f;
      acc[m][n] = fv;
    }

  // ---- compensation: 8 bf16 K-tiles (K=256), simple single-buffer loop.
  for (int ct = 0; ct < NTC; ++ct) {
    const size_t ke = (size_t)ct * 64;  // 32 els * 2B
    async16(gAc + ke, (void*)(ldsb + tid * 16));
    async16(gAc + (size_t)128 * KO_PAD * 2 + ke, (void*)(ldsb + 8192 + tid * 16));
    async16(gBc + ke, (void*)(ldsb + 16384 + tid * 16));
    async16(gBc + (size_t)128 * KO_PAD * 2 + ke, (void*)(ldsb + 24576 + tid * 16));
    __syncthreads();  // drains vmcnt -> tile visible
    bf16x8 ac[8], bc[4];
#pragma unroll
    for (int m = 0; m < 8; ++m)
      ac[m] = *(const bf16x8*)(ldsb + aRd + m * 1024);
#pragma unroll
    for (int n = 0; n < 4; ++n)
      bc[n] = *(const bf16x8*)(ldsb + bRd + n * 1024);
#pragma unroll
    for (int m = 0; m < 8; ++m)
#pragma unroll
      for (int n = 0; n < 4; ++n)
        acc[m][n] = __builtin_amdgcn_mfma_f32_16x16x32_bf16(ac[m], bc[n],
                                                            acc[m][n], 0, 0, 0);
    __syncthreads();  // reads done before next stage overwrites
  }

  // C/D layout: col=lane&15, row=(lane>>4)*4+j [m89/m91; dtype-independent]
  const int cr = (lane >> 4) * 4;
  const int cc = lane & 15;
#pragma unroll
  for (int m = 0; m < 8; ++m) {
#pragma unroll
    for (int n = 0; n < 4; ++n) {
      float* cp = C + (size_t)(bmRow + wm + m * 16 + cr) * N_DIM +
                  (bnRow + wn + n * 16 + cc);
#pragma unroll
      for (int jj = 0; jj < 4; ++jj) cp[(size_t)jj * N_DIM] = acc[m][n][jj];
    }
  }
#undef MFMA_I8
}

// ================== fallback path (bf16, verified round 2) ==================
__global__ __launch_bounds__(256) void prep_x_kernel(const float* __restrict__ x,
                                                     const int* __restrict__ idx,
                                                     __bf16* __restrict__ A, int no,
                                                     int m0) {
  int gid = blockIdx.x * 256 + threadIdx.x;
  int ml = gid / (K_PAD / 8);
  int kk = (gid - ml * (K_PAD / 8)) * 8;
  const float* xr = x + (size_t)(m0 + ml) * K_DIM;
  bf16x8 r;
  if (kk < K_DIM) {
    float4 v0 = *(const float4*)(xr + kk);
    float4 v1 = *(const float4*)(xr + kk + 4);
    r[0] = qbf(v0.x); r[1] = qbf(v0.y); r[2] = qbf(v0.z); r[3] = qbf(v0.w);
    r[4] = qbf(v1.x); r[5] = qbf(v1.y); r[6] = qbf(v1.z); r[7] = qbf(v1.w);
  } else {
    int j = kk - K_DIM;
#pragma unroll
    for (int u = 0; u < 8; ++u) {
      float v = 0.f;
      int jj = j + u;
      if (jj < no) {
        float xv = xr[idx[jj]];
        v = xv - qf(xv);
      }
      r[u] = (__bf16)v;
    }
  }
  *(bf16x8*)(A + (size_t)ml * K_PAD + kk) = r;
}

__global__ __launch_bounds__(256) void prep_w_kernel(const float* __restrict__ w,
                                                     const float* __restrict__ arc,
                                                     __bf16* __restrict__ B, int no,
                                                     int n0) {
  int gid = blockIdx.x * 256 + threadIdx.x;
  int ol = gid / (K_PAD / 8);
  int kk = (gid - ol * (K_PAD / 8)) * 8;
  int o = n0 + ol;
  bf16x8 r;
  if (kk < K_DIM) {
    const float* wr = w + (size_t)o * K_DIM;
    float4 v0 = *(const float4*)(wr + kk);
    float4 v1 = *(const float4*)(wr + kk + 4);
    r[0] = qbf(v0.x); r[1] = qbf(v0.y); r[2] = qbf(v0.z); r[3] = qbf(v0.w);
    r[4] = qbf(v1.x); r[5] = qbf(v1.y); r[6] = qbf(v1.z); r[7] = qbf(v1.w);
  } else {
    int j = kk - K_DIM;
#pragma unroll
    for (int u = 0; u < 8; ++u) {
      float v = 0.f;
      int jj = j + u;
      if (jj < no) v = arc[(size_t)o * no + jj];
      r[u] = (__bf16)v;
    }
  }
  *(bf16x8*)(B + (size_t)ol * K_PAD + kk) = r;
}

__global__ __launch_bounds__(256) void gemm_bt_kernel(const __bf16* __restrict__ A,
                                                      const __bf16* __restrict__ B,
                                                      float* __restrict__ C,
                                                      int m0, int n0, int mtiles) {
  __shared__ __align__(16) __bf16 sA[128 * 64];
  __shared__ __align__(16) __bf16 sB[128 * 64];
  const int bid = blockIdx.x;
  const int bm = bid % mtiles;
  const int bn = bid / mtiles;
  const int t = threadIdx.x;
  const int lane = t & 63;
  const int w = t >> 6;
  const int wm = (w >> 1) * 64;
  const int wn = (w & 1) * 64;
  f32x4 acc[4][4] = {};
  const __bf16* gA = A + (size_t)(bm * 128 + (t >> 3)) * K_PAD + (t & 7) * 8;
  const __bf16* gB = B + (size_t)(bn * 128 + (t >> 3)) * K_PAD + (t & 7) * 8;
  char* lA = (char*)sA + t * 16;
  char* lB = (char*)sB + t * 16;
  const int fr = lane & 15;
  const int fo = (lane >> 4) * 8;
  for (int kt = 0; kt < K_PAD / 64; ++kt) {
    const int k0 = kt * 64;
#pragma unroll
    for (int i = 0; i < 4; ++i) {
      async16(gA + k0 + (size_t)i * 32 * K_PAD, lA + i * 4096);
      async16(gB + k0 + (size_t)i * 32 * K_PAD, lB + i * 4096);
    }
    __syncthreads();
#pragma unroll
    for (int kk = 0; kk < 2; ++kk) {
      bf16x8 aF[4], bF[4];
#pragma unroll
      for (int mt = 0; mt < 4; ++mt)
        aF[mt] = *(const bf16x8*)&sA[(wm + mt * 16 + fr) * 64 + kk * 32 + fo];
#pragma unroll
      for (int nt = 0; nt < 4; ++nt)
        bF[nt] = *(const bf16x8*)&sB[(wn + nt * 16 + fr) * 64 + kk * 32 + fo];
#pragma unroll
      for (int mt = 0; mt < 4; ++mt)
#pragma unroll
        for (int nt = 0; nt < 4; ++nt)
          acc[mt][nt] = __builtin_amdgcn_mfma_f32_16x16x32_bf16(
              aF[mt], bF[nt], acc[mt][nt], 0, 0, 0);
    }
    __syncthreads();
  }
  const int cr = (lane >> 4) * 4;
  const int cc = lane & 15;
#pragma unroll
  for (int mt = 0; mt < 4; ++mt)
#pragma unroll
    for (int nt = 0; nt < 4; ++nt) {
      float* cp = C + (size_t)(m0 + bm * 128 + wm + mt * 16 + cr) * N_DIM +
                  (n0 + bn * 128 + wn + nt * 16 + cc);
#pragma unroll
      for (int jj = 0; jj < 4; ++jj) cp[(size_t)jj * N_DIM] = acc[mt][nt][jj];
    }
}

__global__ __launch_bounds__(256) void naive_kernel(const float* __restrict__ x,
                                                    const float* __restrict__ w,
                                                    const float* __restrict__ arc,
                                                    const int* __restrict__ idx,
                                                    float* __restrict__ out, int no) {
  size_t gid = (size_t)blockIdx.x * 256 + threadIdx.x;
  if (gid >= (size_t)M_DIM * N_DIM) return;
  int m = (int)(gid / N_DIM), o = (int)(gid % N_DIM);
  const float* xr = x + (size_t)m * K_DIM;
  const float* wr = w + (size_t)o * K_DIM;
  float acc = 0.f;
  for (int k = 0; k < K_DIM; ++k) acc += qf(xr[k]) * qf(wr[k]);
  for (int j = 0; j < no; ++j) {
    float xv = xr[idx[j]];
    acc += (xv - qf(xv)) * arc[(size_t)o * no + j];
  }
  out[gid] = acc;
}

extern "C" void kernel_launch(void* const* d_in, const int* in_sizes, int n_in,
                              void* d_out, int out_size, void* d_ws, size_t ws_size,
                              hipStream_t stream) {
  const float* x = (const float*)d_in[0];     // (4,2048,4096)
  const float* wgt = (const float*)d_in[1];   // (4096,4096)
  const float* arc = (const float*)d_in[2];   // (4096,204)
  const int* idx = (const int*)d_in[3];       // (204,)
  float* out = (float*)d_out;                 // (4,2048,4096) fp32
  const int no = in_sizes[3];                 // 204

  const size_t FAST_WS = (size_t)M_DIM * K_DIM + (size_t)N_DIM * K_DIM +
                         (size_t)M_DIM * KO_PAD * 2 + (size_t)N_DIM * KO_PAD * 2;
  if (ws_size >= FAST_WS) {
    char* A8 = (char*)d_ws;
    char* B8 = A8 + (size_t)M_DIM * K_DIM;
    __bf16* Acp = (__bf16*)(B8 + (size_t)N_DIM * K_DIM);
    __bf16* Bcp = Acp + (size_t)M_DIM * KO_PAD;
    const int xb = M_DIM * GRP / 256;         // x-prep blocks
    const int wb = N_DIM * GRP / 256;         // w-prep blocks
    prep_fused_kernel<<<xb + wb, 256, 0, stream>>>(x, idx, wgt, arc, A8, Acp, B8,
                                                   Bcp, no, xb);
    gemm_i8_kernel<<<(M_DIM / 256) * (N_DIM / 256), 512, 0, stream>>>(A8, B8, Acp,
                                                                      Bcp, out);
    return;
  }

  // chunked bf16 fallback (verified round 2)
  const size_t rowb = (size_t)K_PAD * sizeof(__bf16);
  const size_t rows_avail = ws_size / rowb;
  size_t nr_c, mr_c;
  if (rows_avail >= (size_t)(N_DIM + 128)) {
    nr_c = N_DIM;
    mr_c = ((rows_avail - N_DIM) / 128) * 128;
    if (mr_c > M_DIM) mr_c = M_DIM;
  } else {
    nr_c = (rows_avail / 2 / 128) * 128;
    if (nr_c > N_DIM) nr_c = N_DIM;
    mr_c = nr_c ? (((rows_avail - nr_c) / 128) * 128) : 0;
    if (mr_c > M_DIM) mr_c = M_DIM;
  }
  if (nr_c == 0 || mr_c == 0) {
    size_t total = (size_t)M_DIM * N_DIM;
    naive_kernel<<<(int)((total + 255) / 256), 256, 0, stream>>>(x, wgt, arc, idx, out, no);
    return;
  }
  __bf16* B = (__bf16*)d_ws;
  __bf16* A = B + nr_c * (size_t)K_PAD;
  for (int n0 = 0; n0 < N_DIM; n0 += (int)nr_c) {
    const int nr = (int)((N_DIM - n0 < (int)nr_c) ? (N_DIM - n0) : (int)nr_c);
    prep_w_kernel<<<nr * (K_PAD / 8) / 256, 256, 0, stream>>>(wgt, arc, B, no, n0);
    for (int m0 = 0; m0 < M_DIM; m0 += (int)mr_c) {
      const int mr = (int)((M_DIM - m0 < (int)mr_c) ? (M_DIM - m0) : (int)mr_c);
      prep_x_kernel<<<mr * (K_PAD / 8) / 256, 256, 0, stream>>>(x, idx, A, no, m0);
      const int mtiles = mr / 128, ntiles = nr / 128;
      gemm_bt_kernel<<<mtiles * ntiles, 256, 0, stream>>>(A, B, out, m0, n0, mtiles);
    }
  }
}